// Round 6
// baseline (274.970 us; speedup 1.0000x reference)
//
#include <hip/hip_runtime.h>
#include <math.h>

namespace {

constexpr int kB = 16, kT = 32, kN = 64, kE = 64, kFIN = 2, kD = 64, kH = 4, kL = 2, kSH = 128;
constexpr int kG = kB * kT;    // 512 graphs
constexpr int kET = kE + kN;   // 128 edges incl. self loops

// ---------------- GAT LDS layout (float indices) ----------------
constexpr int HN   = 0;                    // h[n][k] stride 68 (4352)
constexpr int XLo  = HN + 64 * 68;         // xl[4][64*65] (xl[hh*4160 + n*65 + d]) (16640)
constexpr int WREG = XLo + 4 * 4160;       // W staged [256][68] (17408); xr[4][4160] lives here too
constexpr int XRo  = WREG;
constexpr int LG   = WREG + 256 * 68;      // logitT[4][128]
constexpr int AL   = LG + 4 * 128;         // alphaT[4][128]
constexpr int MB   = AL + 4 * 128;         // mT[4][64]
constexpr int SB   = MB + 4 * 64;          // 1/sum T[4][64]
constexpr int FEND = SB + 4 * 64;          // 39936 floats
// int section
constexpr int ISRC = 0, IDST = 128, IOFF = 256, IEL = 321;
constexpr int NINT = IEL + 128;            // 449 ints
constexpr size_t GAT_LDS = size_t(FEND) * 4 + size_t(NINT) * 4;  // 161,540 B <= 163,840

// ---------------- LSTM LDS layout ----------------
constexpr int ES  = 0;                     // embS[32][64] (2048); reused as h-final[128] at the end
constexpr int YS  = ES + 32 * 64;          // ys[32][128] (4096)
constexpr int ZB2 = YS + 32 * 128;         // gate dbuf [2][512] (1024)
constexpr int ZX  = ZB2 + 2 * 512;         // zx[32][512] (16384)
constexpr int LSTM_FLOATS = ZX + 32 * 512; // 23552
constexpr size_t LSTM_LDS = size_t(LSTM_FLOATS) * 4;  // 94,208 B

__device__ __forceinline__ float fsig(float x) {
    return __builtin_amdgcn_rcpf(1.f + __expf(-x));
}
__device__ __forceinline__ float ftanh(float x) {
    return 1.f - 2.f * __builtin_amdgcn_rcpf(1.f + __expf(2.f * x));
}
__device__ __forceinline__ float rlane(float v, int l) {
    return __builtin_bit_cast(float, __builtin_amdgcn_readlane(__builtin_bit_cast(int, v), l));
}

} // namespace

// =====================================================================
// GAT kernel: one block per graph, 1024 threads (16 waves, 4/SIMD).
// Transforms: 4n x 4c register tiles, conflict-free k-major reads.
// LayerNorm fully in registers via 64-lane shfl_xor butterfly.
// =====================================================================
__global__ __launch_bounds__(1024, 1)
void gat_kernel(const float* __restrict__ x, const int* __restrict__ eidx,
                const float* __restrict__ projW, const float* __restrict__ projb,
                const float* __restrict__ gWl, const float* __restrict__ gWr,
                const float* __restrict__ gatt, const float* __restrict__ gb,
                const float* __restrict__ lng, const float* __restrict__ lnb,
                float* __restrict__ emb)
{
    extern __shared__ float sm[];
    int* ib = (int*)(sm + FEND);
    const int g = blockIdx.x;
    const int t = threadIdx.x;

    // ---- edges + self loops ----
    if (t < kET) {
        int s, d;
        if (t < kE) { s = eidx[g * 2 * kE + t]; d = eidx[g * 2 * kE + kE + t]; }
        else        { s = t - kE; d = s; }
        ib[ISRC + t] = s;
        ib[IDST + t] = d;
    }
    // ---- input projection + ReLU -> h[n][k] (stride 68) ----
    #pragma unroll
    for (int r = 0; r < 4; ++r) {
        int p = t + 1024 * r;
        int d = p & 63, n = p >> 6;           // n wave-uniform, d = lane
        float x0 = x[g * kN * kFIN + n * kFIN + 0];
        float x1 = x[g * kN * kFIN + n * kFIN + 1];
        float v = fmaf(x0, projW[d * kFIN + 0], fmaf(x1, projW[d * kFIN + 1], projb[d]));
        sm[HN + n * 68 + d] = fmaxf(v, 0.f);
    }
    __syncthreads();
    // ---- CSR build (deterministic, no atomics) ----
    if (t < kN) {
        int c = 0;
        for (int e = 0; e < kET; ++e) c += (ib[IDST + e] == t) ? 1 : 0;
        ib[IOFF + t + 1] = c;
    }
    __syncthreads();
    if (t == 0) {
        ib[IOFF + 0] = 0;
        for (int n = 0; n < kN; ++n) ib[IOFF + n + 1] += ib[IOFF + n];
    }
    __syncthreads();
    if (t < kN) {
        int pos = ib[IOFF + t];
        for (int e = 0; e < kET; ++e)
            if (ib[IDST + e] == t) ib[IEL + pos++] = e;
    }
    __syncthreads();

    const int wv = t >> 6;        // wave 0..15
    const int ln = t & 63;
    const int cl = ln & 7;        // c-lane 0..7
    const int ng = ln >> 3;       // n-group 0..7
    const int nO = (wv & 1) * 32; // n-half per wave
    const int cO = (wv >> 1) * 32;// c-range per wave (8 ranges x 32)

    for (int l = 0; l < kL; ++l) {
        // ======== transforms: half 0 -> xl (XLo), half 1 -> xr (WREG, overwrites W) ========
        for (int half = 0; half < 2; ++half) {
            const float* Wg = (half ? gWr : gWl) + l * 256 * 64;
            // stage W[c][k] stride 68 (pure float4 sweep)
            #pragma unroll
            for (int it = 0; it < 4; ++it) {
                int p = t + 1024 * it;              // float4 index into W [256][64]
                float4 v = ((const float4*)Wg)[p];
                int c = p >> 4, k4 = p & 15;
                *(float4*)&sm[WREG + c * 68 + k4 * 4] = v;
            }
            __syncthreads();
            float acc[4][4];
            #pragma unroll
            for (int i = 0; i < 4; ++i)
                #pragma unroll
                for (int j = 0; j < 4; ++j) acc[i][j] = 0.f;
            #pragma unroll 4
            for (int k4 = 0; k4 < 16; ++k4) {
                float4 h4[4], w4[4];
                #pragma unroll
                for (int i = 0; i < 4; ++i)
                    h4[i] = *(const float4*)&sm[HN + (nO + ng + 8 * (i & 3) + 0) * 68 + k4 * 4];
                #pragma unroll
                for (int i = 0; i < 4; ++i)
                    h4[i] = *(const float4*)&sm[HN + (nO + ng + 8 * i) * 68 + k4 * 4];
                #pragma unroll
                for (int j = 0; j < 4; ++j)
                    w4[j] = *(const float4*)&sm[WREG + (cO + cl + 8 * j) * 68 + k4 * 4];
                #pragma unroll
                for (int i = 0; i < 4; ++i)
                    #pragma unroll
                    for (int j = 0; j < 4; ++j) {
                        acc[i][j] = fmaf(h4[i].x, w4[j].x, acc[i][j]);
                        acc[i][j] = fmaf(h4[i].y, w4[j].y, acc[i][j]);
                        acc[i][j] = fmaf(h4[i].z, w4[j].z, acc[i][j]);
                        acc[i][j] = fmaf(h4[i].w, w4[j].w, acc[i][j]);
                    }
            }
            __syncthreads();   // drain W reads before overwriting WREG
            float* dst = sm + (half ? XRo : XLo);
            #pragma unroll
            for (int i = 0; i < 4; ++i) {
                int n = nO + ng + 8 * i;
                #pragma unroll
                for (int j = 0; j < 4; ++j) {
                    int c = cO + cl + 8 * j;
                    dst[(c >> 6) * 4160 + n * 65 + (c & 63)] = acc[i][j];
                }
            }
            __syncthreads();
        }
        // ---- edge logits (threads 0..511) ----
        if (t < 512) {
            const int e = t & 127, hh = t >> 7;
            const int s = ib[ISRC + e], d_ = ib[IDST + e];
            const float* av = gatt + (l * kH + hh) * kD;
            const float* pl = sm + XLo + hh * 4160 + s * 65;
            const float* pr = sm + XRo + hh * 4160 + d_ * 65;
            float a0 = 0.f, a1 = 0.f, a2 = 0.f, a3 = 0.f;
            #pragma unroll 4
            for (int dd = 0; dd < 64; dd += 4) {
                float v0 = pl[dd+0] + pr[dd+0]; v0 = (v0 > 0.f) ? v0 : 0.2f * v0;
                float v1 = pl[dd+1] + pr[dd+1]; v1 = (v1 > 0.f) ? v1 : 0.2f * v1;
                float v2 = pl[dd+2] + pr[dd+2]; v2 = (v2 > 0.f) ? v2 : 0.2f * v2;
                float v3 = pl[dd+3] + pr[dd+3]; v3 = (v3 > 0.f) ? v3 : 0.2f * v3;
                a0 = fmaf(av[dd+0], v0, a0);
                a1 = fmaf(av[dd+1], v1, a1);
                a2 = fmaf(av[dd+2], v2, a2);
                a3 = fmaf(av[dd+3], v3, a3);
            }
            sm[LG + hh * 128 + e] = (a0 + a1) + (a2 + a3);
        }
        __syncthreads();
        // ---- segment max & sum ----
        if (t < 256) {
            const int n = t & 63, hh = t >> 6;
            const int i0 = ib[IOFF + n], i1 = ib[IOFF + n + 1];
            float m = -3.0e38f;
            for (int i = i0; i < i1; ++i) m = fmaxf(m, sm[LG + hh * 128 + ib[IEL + i]]);
            float ssum = 0.f;
            for (int i = i0; i < i1; ++i) ssum += __expf(sm[LG + hh * 128 + ib[IEL + i]] - m);
            sm[MB + hh * 64 + n] = m;
            sm[SB + hh * 64 + n] = __builtin_amdgcn_rcpf(ssum);
        }
        __syncthreads();
        // ---- alpha ----
        if (t < 512) {
            const int e = t & 127, hh = t >> 7;
            const int d_ = ib[IDST + e];
            sm[AL + hh * 128 + e] =
                __expf(sm[LG + hh * 128 + e] - sm[MB + hh * 64 + d_]) * sm[SB + hh * 64 + d_];
        }
        __syncthreads();
        // ---- aggregate + head-mean + bias + LAYERNORM (in registers) -> h[n][k] ----
        // thread owns (n = wave-uniform, dd = lane): whole row per wave -> shfl reduce
        #pragma unroll
        for (int r = 0; r < 4; ++r) {
            int p = t + 1024 * r;
            int n = p >> 6, dd = p & 63;
            const int i0 = ib[IOFF + n], i1 = ib[IOFF + n + 1];
            float acc = 0.f;
            for (int i = i0; i < i1; ++i) {
                int e = ib[IEL + i];
                int s = ib[ISRC + e];
                const float* xs = sm + XLo + s * 65 + dd;
                acc = fmaf(sm[AL + 0 * 128 + e], xs[0 * 4160], acc);
                acc = fmaf(sm[AL + 1 * 128 + e], xs[1 * 4160], acc);
                acc = fmaf(sm[AL + 2 * 128 + e], xs[2 * 4160], acc);
                acc = fmaf(sm[AL + 3 * 128 + e], xs[3 * 4160], acc);
            }
            float v = acc * 0.25f + gb[l * kD + dd];
            // wave-level LN over the 64 lanes (row n)
            float s1 = v, s2 = v * v;
            #pragma unroll
            for (int m = 1; m < 64; m <<= 1) {
                s1 += __shfl_xor(s1, m);
                s2 += __shfl_xor(s2, m);
            }
            float mu  = s1 * (1.f / 64.f);
            float var = s2 * (1.f / 64.f) - mu * mu;
            float rs  = rsqrtf(var + 1e-5f);
            float y   = fmaf(lng[l * kD + dd] * (v - mu), rs, lnb[l * kD + dd]);
            sm[HN + n * 68 + dd] = fmaxf(y, 0.f);
        }
        __syncthreads();
    }
    // ---- global mean pool ----
    if (t < kD) {
        float s = 0.f;
        #pragma unroll 8
        for (int n = 0; n < kN; ++n) s += sm[HN + n * 68 + t];
        emb[g * kD + t] = s * (1.f / 64.f);
    }
}

// =====================================================================
// LSTM (2 layers, T=32) + MLP head: one block per batch element (16),
// 512 threads. h,c live in per-wave REGISTERS (redundant copies);
// gates via double-buffered ZB -> ONE barrier per step.
// =====================================================================
__global__ __launch_bounds__(512, 1)
void lstm_head_kernel(const float* __restrict__ emb,
                      const float* __restrict__ W0ih, const float* __restrict__ W0hh,
                      const float* __restrict__ b0ih, const float* __restrict__ b0hh,
                      const float* __restrict__ W1ih, const float* __restrict__ W1hh,
                      const float* __restrict__ b1ih, const float* __restrict__ b1hh,
                      const float* __restrict__ hW1, const float* __restrict__ hb1,
                      const float* __restrict__ hW2, const float* __restrict__ hb2,
                      const float* __restrict__ hW3, const float* __restrict__ hb3,
                      float* __restrict__ outp)
{
    extern __shared__ float sm[];
    const int bb = blockIdx.x;
    const int j  = threadIdx.x;      // 0..511
    const int ln = j & 63;
    const int gate = j >> 7;         // 0:i 1:f 2:g 3:o (wave-uniform)

    ((float4*)(sm + ES))[j] = ((const float4*)(emb + bb * kT * kD))[j];
    __syncthreads();

    // ---- layer0 x-part: zx[t][j] = bias + W0ih[j,:]·emb[t,:] ----
    {
        float w[64];
        const float4* wr = (const float4*)(W0ih + j * 64);
        #pragma unroll
        for (int k4 = 0; k4 < 16; ++k4) {
            float4 v = wr[k4];
            w[4*k4+0] = v.x; w[4*k4+1] = v.y; w[4*k4+2] = v.z; w[4*k4+3] = v.w;
        }
        const float bias = b0ih[j] + b0hh[j];
        for (int tt = 0; tt < kT; ++tt) {
            float ev = sm[ES + tt * 64 + ln];
            float a0 = bias, a1 = 0.f, a2 = 0.f, a3 = 0.f;
            #pragma unroll
            for (int k = 0; k < 64; k += 4) {
                a0 = fmaf(w[k + 0], rlane(ev, k + 0), a0);
                a1 = fmaf(w[k + 1], rlane(ev, k + 1), a1);
                a2 = fmaf(w[k + 2], rlane(ev, k + 2), a2);
                a3 = fmaf(w[k + 3], rlane(ev, k + 3), a3);
            }
            sm[ZX + tt * 512 + j] = (a0 + a1) + (a2 + a3);
        }
    }
    __syncthreads();
    // ---- layer0 recurrence (h,c in registers; 1 barrier/step) ----
    {
        float w[128];
        const float4* wr = (const float4*)(W0hh + j * 128);
        #pragma unroll
        for (int k4 = 0; k4 < 32; ++k4) {
            float4 v = wr[k4];
            w[4*k4+0] = v.x; w[4*k4+1] = v.y; w[4*k4+2] = v.z; w[4*k4+3] = v.w;
        }
        float hlo = 0.f, hhi = 0.f, clo = 0.f, chi = 0.f;
        for (int tt = 0; tt < kT; ++tt) {
            float a0 = sm[ZX + tt * 512 + j], a1 = 0.f, a2 = 0.f, a3 = 0.f;
            #pragma unroll
            for (int k = 0; k < 64; k += 4) {
                a0 = fmaf(w[k + 0], rlane(hlo, k + 0), a0);
                a1 = fmaf(w[k + 1], rlane(hlo, k + 1), a1);
                a2 = fmaf(w[k + 2], rlane(hlo, k + 2), a2);
                a3 = fmaf(w[k + 3], rlane(hlo, k + 3), a3);
            }
            #pragma unroll
            for (int k = 0; k < 64; k += 4) {
                a0 = fmaf(w[64 + k + 0], rlane(hhi, k + 0), a0);
                a1 = fmaf(w[64 + k + 1], rlane(hhi, k + 1), a1);
                a2 = fmaf(w[64 + k + 2], rlane(hhi, k + 2), a2);
                a3 = fmaf(w[64 + k + 3], rlane(hhi, k + 3), a3);
            }
            float zv = (a0 + a1) + (a2 + a3);
            const int zbase = ZB2 + (tt & 1) * 512;
            sm[zbase + j] = (gate == 2) ? ftanh(zv) : fsig(zv);
            __syncthreads();
            float i0 = sm[zbase + ln],      f0 = sm[zbase + 128 + ln];
            float g0 = sm[zbase + 256 + ln], o0 = sm[zbase + 384 + ln];
            float i1 = sm[zbase + 64 + ln],  f1 = sm[zbase + 192 + ln];
            float g1 = sm[zbase + 320 + ln], o1 = sm[zbase + 448 + ln];
            clo = fmaf(f0, clo, i0 * g0);  hlo = o0 * ftanh(clo);
            chi = fmaf(f1, chi, i1 * g1);  hhi = o1 * ftanh(chi);
            if (j < 64) { sm[YS + tt * 128 + ln] = hlo; sm[YS + tt * 128 + 64 + ln] = hhi; }
        }
    }
    __syncthreads();
    // ---- layer1 x-part: zx[t][j] = bias + W1ih[j,:]·ys[t,:] ----
    {
        float w[128];
        const float4* wr = (const float4*)(W1ih + j * 128);
        #pragma unroll
        for (int k4 = 0; k4 < 32; ++k4) {
            float4 v = wr[k4];
            w[4*k4+0] = v.x; w[4*k4+1] = v.y; w[4*k4+2] = v.z; w[4*k4+3] = v.w;
        }
        const float bias = b1ih[j] + b1hh[j];
        for (int tt = 0; tt < kT; ++tt) {
            float ylo = sm[YS + tt * 128 + ln];
            float yhi = sm[YS + tt * 128 + 64 + ln];
            float a0 = bias, a1 = 0.f, a2 = 0.f, a3 = 0.f;
            #pragma unroll
            for (int k = 0; k < 64; k += 4) {
                a0 = fmaf(w[k + 0], rlane(ylo, k + 0), a0);
                a1 = fmaf(w[k + 1], rlane(ylo, k + 1), a1);
                a2 = fmaf(w[k + 2], rlane(ylo, k + 2), a2);
                a3 = fmaf(w[k + 3], rlane(ylo, k + 3), a3);
            }
            #pragma unroll
            for (int k = 0; k < 64; k += 4) {
                a0 = fmaf(w[64 + k + 0], rlane(yhi, k + 0), a0);
                a1 = fmaf(w[64 + k + 1], rlane(yhi, k + 1), a1);
                a2 = fmaf(w[64 + k + 2], rlane(yhi, k + 2), a2);
                a3 = fmaf(w[64 + k + 3], rlane(yhi, k + 3), a3);
            }
            sm[ZX + tt * 512 + j] = (a0 + a1) + (a2 + a3);
        }
    }
    __syncthreads();
    // ---- layer1 recurrence ----
    {
        float w[128];
        const float4* wr = (const float4*)(W1hh + j * 128);
        #pragma unroll
        for (int k4 = 0; k4 < 32; ++k4) {
            float4 v = wr[k4];
            w[4*k4+0] = v.x; w[4*k4+1] = v.y; w[4*k4+2] = v.z; w[4*k4+3] = v.w;
        }
        float hlo = 0.f, hhi = 0.f, clo = 0.f, chi = 0.f;
        for (int tt = 0; tt < kT; ++tt) {
            float a0 = sm[ZX + tt * 512 + j], a1 = 0.f, a2 = 0.f, a3 = 0.f;
            #pragma unroll
            for (int k = 0; k < 64; k += 4) {
                a0 = fmaf(w[k + 0], rlane(hlo, k + 0), a0);
                a1 = fmaf(w[k + 1], rlane(hlo, k + 1), a1);
                a2 = fmaf(w[k + 2], rlane(hlo, k + 2), a2);
                a3 = fmaf(w[k + 3], rlane(hlo, k + 3), a3);
            }
            #pragma unroll
            for (int k = 0; k < 64; k += 4) {
                a0 = fmaf(w[64 + k + 0], rlane(hhi, k + 0), a0);
                a1 = fmaf(w[64 + k + 1], rlane(hhi, k + 1), a1);
                a2 = fmaf(w[64 + k + 2], rlane(hhi, k + 2), a2);
                a3 = fmaf(w[64 + k + 3], rlane(hhi, k + 3), a3);
            }
            float zv = (a0 + a1) + (a2 + a3);
            const int zbase = ZB2 + (tt & 1) * 512;
            sm[zbase + j] = (gate == 2) ? ftanh(zv) : fsig(zv);
            __syncthreads();
            float i0 = sm[zbase + ln],      f0 = sm[zbase + 128 + ln];
            float g0 = sm[zbase + 256 + ln], o0 = sm[zbase + 384 + ln];
            float i1 = sm[zbase + 64 + ln],  f1 = sm[zbase + 192 + ln];
            float g1 = sm[zbase + 320 + ln], o1 = sm[zbase + 448 + ln];
            clo = fmaf(f0, clo, i0 * g0);  hlo = o0 * ftanh(clo);
            chi = fmaf(f1, chi, i1 * g1);  hhi = o1 * ftanh(chi);
            if (tt == kT - 1 && j < 64) { sm[ES + ln] = hlo; sm[ES + 64 + ln] = hhi; }
        }
    }
    __syncthreads();
    // ---- MLP head (final h in sm[ES..ES+128)) ----
    if (j < 64) {
        float a0 = hb1[j], a1 = 0.f;
        #pragma unroll 8
        for (int k = 0; k < 128; k += 2) {
            a0 = fmaf(hW1[j * 128 + k],     sm[ES + k],     a0);
            a1 = fmaf(hW1[j * 128 + k + 1], sm[ES + k + 1], a1);
        }
        sm[ZB2 + j] = fmaxf(a0 + a1, 0.f);
    }
    __syncthreads();
    if (j < 32) {
        float acc = hb2[j];
        #pragma unroll 8
        for (int k = 0; k < 64; ++k) acc = fmaf(hW2[j * 64 + k], sm[ZB2 + k], acc);
        sm[ZB2 + 64 + j] = fmaxf(acc, 0.f);
    }
    __syncthreads();
    if (j == 0) {
        float acc = hb3[0];
        #pragma unroll
        for (int k = 0; k < 32; ++k) acc = fmaf(hW3[k], sm[ZB2 + 64 + k], acc);
        outp[bb] = fsig(acc);
    }
}

extern "C" void kernel_launch(void* const* d_in, const int* in_sizes, int n_in,
                              void* d_out, int out_size, void* d_ws, size_t ws_size,
                              hipStream_t stream) {
    const float* x     = (const float*)d_in[0];
    const int*   eidx  = (const int*)  d_in[1];
    const float* projW = (const float*)d_in[2];
    const float* projb = (const float*)d_in[3];
    const float* gWl   = (const float*)d_in[4];
    const float* gWr   = (const float*)d_in[5];
    const float* gatt  = (const float*)d_in[6];
    const float* gb    = (const float*)d_in[7];
    const float* lng   = (const float*)d_in[8];
    const float* lnb   = (const float*)d_in[9];
    const float* W0ih  = (const float*)d_in[10];
    const float* W0hh  = (const float*)d_in[11];
    const float* b0ih  = (const float*)d_in[12];
    const float* b0hh  = (const float*)d_in[13];
    const float* W1ih  = (const float*)d_in[14];
    const float* W1hh  = (const float*)d_in[15];
    const float* b1ih  = (const float*)d_in[16];
    const float* b1hh  = (const float*)d_in[17];
    const float* hW1   = (const float*)d_in[18];
    const float* hb1   = (const float*)d_in[19];
    const float* hW2   = (const float*)d_in[20];
    const float* hb2   = (const float*)d_in[21];
    const float* hW3   = (const float*)d_in[22];
    const float* hb3   = (const float*)d_in[23];
    float* outp = (float*)d_out;
    float* emb  = (float*)d_ws;   // [512][64] fp32 scratch

    (void)hipFuncSetAttribute((const void*)gat_kernel,
                              hipFuncAttributeMaxDynamicSharedMemorySize, (int)GAT_LDS);
    (void)hipFuncSetAttribute((const void*)lstm_head_kernel,
                              hipFuncAttributeMaxDynamicSharedMemorySize, (int)LSTM_LDS);

    hipLaunchKernelGGL(gat_kernel, dim3(kG), dim3(1024), GAT_LDS, stream,
                       x, eidx, projW, projb, gWl, gWr, gatt, gb, lng, lnb, emb);
    hipLaunchKernelGGL(lstm_head_kernel, dim3(kB), dim3(512), LSTM_LDS, stream,
                       emb, W0ih, W0hh, b0ih, b0hh, W1ih, W1hh, b1ih, b1hh,
                       hW1, hb1, hW2, hb2, hW3, hb3, outp);
}

// Round 7
// 244.783 us; speedup vs baseline: 1.1233x; 1.1233x over previous
//
#include <hip/hip_runtime.h>
#include <math.h>

namespace {

constexpr int kB = 16, kT = 32, kN = 64, kE = 64, kFIN = 2, kD = 64, kH = 4, kL = 2, kSH = 128;
constexpr int kG = kB * kT;    // 512 graphs
constexpr int kET = kE + kN;   // 128 edges incl. self loops

// ---------------- GAT LDS layout (float indices) ----------------
constexpr int HN   = 0;                    // h[n][k] f32, stride 68 (4352)
constexpr int XLo  = HN + 64 * 68;         // xl[4][64*65] (xl[hh*4160 + n*65 + d])
constexpr int XRo  = XLo + 4 * 4160;       // xr[4][64*65]
constexpr int LG   = XRo + 4 * 4160;       // logitT[4][128]
constexpr int AL   = LG + 4 * 128;         // alphaT[4][128]
constexpr int MB   = AL + 4 * 128;         // mT[4][64]
constexpr int SB   = MB + 4 * 64;          // 1/sum T[4][64]
constexpr int FEND = SB + 4 * 64;          // 39168 floats
// int section
constexpr int ISRC = 0, IDST = 128, IOFF = 256, IEL = 321;
constexpr int NINT = IEL + 128;            // 449 ints
constexpr size_t GAT_LDS = size_t(FEND) * 4 + size_t(NINT) * 4;  // 158,468 B

// ---------------- LSTM LDS layout ----------------
constexpr int ES  = 0;                     // embS[32][64]; reused as h-final[128]
constexpr int YS  = ES + 32 * 64;          // ys[32][128]
constexpr int ZB2 = YS + 32 * 128;         // gate dbuf [2][512]
constexpr int ZX  = ZB2 + 2 * 512;         // zx[32][512]
constexpr int LSTM_FLOATS = ZX + 32 * 512;
constexpr size_t LSTM_LDS = size_t(LSTM_FLOATS) * 4;  // 94,208 B

typedef _Float16 half8 __attribute__((ext_vector_type(8)));
typedef float    f32x4 __attribute__((ext_vector_type(4)));

__device__ __forceinline__ float fsig(float x) {
    return __builtin_amdgcn_rcpf(1.f + __expf(-x));
}
__device__ __forceinline__ float ftanh(float x) {
    return 1.f - 2.f * __builtin_amdgcn_rcpf(1.f + __expf(2.f * x));
}
__device__ __forceinline__ float rlane(float v, int l) {
    return __builtin_bit_cast(float, __builtin_amdgcn_readlane(__builtin_bit_cast(int, v), l));
}

} // namespace

// =====================================================================
// GAT kernel: one block per graph, 1024 threads (16 waves, 4/SIMD).
// Transforms via mfma_f32_16x16x32_f16: A-frags from fp32 h in LDS
// (cvt f16), B-frags = W rows straight from global/L2 (no staging).
// Wave (tn = wv&3, tcg = wv>>2) owns n-tile tn x c-tiles {tcg+4j}.
// =====================================================================
__global__ __launch_bounds__(1024, 1)
void gat_kernel(const float* __restrict__ x, const int* __restrict__ eidx,
                const float* __restrict__ projW, const float* __restrict__ projb,
                const float* __restrict__ gWl, const float* __restrict__ gWr,
                const float* __restrict__ gatt, const float* __restrict__ gb,
                const float* __restrict__ lng, const float* __restrict__ lnb,
                float* __restrict__ emb)
{
    extern __shared__ float sm[];
    int* ib = (int*)(sm + FEND);
    const int g = blockIdx.x;
    const int t = threadIdx.x;

    // ---- edges + self loops ----
    if (t < kET) {
        int s, d;
        if (t < kE) { s = eidx[g * 2 * kE + t]; d = eidx[g * 2 * kE + kE + t]; }
        else        { s = t - kE; d = s; }
        ib[ISRC + t] = s;
        ib[IDST + t] = d;
    }
    // ---- input projection + ReLU -> h[n][k] (f32, stride 68) ----
    #pragma unroll
    for (int r = 0; r < 4; ++r) {
        int p = t + 1024 * r;
        int d = p & 63, n = p >> 6;           // n wave-uniform, d = lane
        float x0 = x[g * kN * kFIN + n * kFIN + 0];
        float x1 = x[g * kN * kFIN + n * kFIN + 1];
        float v = fmaf(x0, projW[d * kFIN + 0], fmaf(x1, projW[d * kFIN + 1], projb[d]));
        sm[HN + n * 68 + d] = fmaxf(v, 0.f);
    }
    __syncthreads();
    // ---- CSR build (deterministic, no atomics) ----
    if (t < kN) {
        int c = 0;
        for (int e = 0; e < kET; ++e) c += (ib[IDST + e] == t) ? 1 : 0;
        ib[IOFF + t + 1] = c;
    }
    __syncthreads();
    if (t == 0) {
        ib[IOFF + 0] = 0;
        for (int n = 0; n < kN; ++n) ib[IOFF + n + 1] += ib[IOFF + n];
    }
    __syncthreads();
    if (t < kN) {
        int pos = ib[IOFF + t];
        for (int e = 0; e < kET; ++e)
            if (ib[IDST + e] == t) ib[IEL + pos++] = e;
    }
    __syncthreads();

    const int wv  = t >> 6;       // wave 0..15
    const int ln  = t & 63;
    const int tn  = wv & 3;       // n-tile (16 rows)
    const int tcg = wv >> 2;      // c-tile group: tiles {tcg, tcg+4, tcg+8, tcg+12}
    const int lr  = ln & 15;      // row (A) / col (B,D)
    const int lg  = ln >> 4;      // k-chunk group 0..3

    for (int l = 0; l < kL; ++l) {
        // ======== transforms (MFMA): half 0 -> xl, half 1 -> xr ========
        for (int half = 0; half < 2; ++half) {
            const float* Wg = (half ? gWr : gWl) + l * 256 * 64;
            f32x4 acc[4];
            #pragma unroll
            for (int jj = 0; jj < 4; ++jj) acc[jj] = (f32x4){0.f, 0.f, 0.f, 0.f};
            #pragma unroll
            for (int q = 0; q < 2; ++q) {
                const int kb = q * 32 + lg * 8;
                // A-fragment: h[16*tn + lr][kb..kb+7] (f32 LDS -> f16)
                const float* hp = &sm[HN + (16 * tn + lr) * 68 + kb];
                float4 hu = *(const float4*)hp;
                float4 hv = *(const float4*)(hp + 4);
                half8 af;
                af[0] = (_Float16)hu.x; af[1] = (_Float16)hu.y;
                af[2] = (_Float16)hu.z; af[3] = (_Float16)hu.w;
                af[4] = (_Float16)hv.x; af[5] = (_Float16)hv.y;
                af[6] = (_Float16)hv.z; af[7] = (_Float16)hv.w;
                #pragma unroll
                for (int jj = 0; jj < 4; ++jj) {
                    // B-fragment: W[16*tc + lr][kb..kb+7] from global (L2-hot)
                    const int c = 16 * (tcg + 4 * jj) + lr;
                    const float* wp = Wg + c * 64 + kb;
                    float4 wu = *(const float4*)wp;
                    float4 wz = *(const float4*)(wp + 4);
                    half8 bf;
                    bf[0] = (_Float16)wu.x; bf[1] = (_Float16)wu.y;
                    bf[2] = (_Float16)wu.z; bf[3] = (_Float16)wu.w;
                    bf[4] = (_Float16)wz.x; bf[5] = (_Float16)wz.y;
                    bf[6] = (_Float16)wz.z; bf[7] = (_Float16)wz.w;
                    acc[jj] = __builtin_amdgcn_mfma_f32_16x16x32_f16(af, bf, acc[jj], 0, 0, 0);
                }
            }
            // D write: col = 16*tc + lr, row n = 16*tn + lg*4 + r
            float* dst = sm + (half ? XRo : XLo);
            #pragma unroll
            for (int jj = 0; jj < 4; ++jj) {
                const int tc = tcg + 4 * jj;
                const int base = (tc >> 2) * 4160 + (tc & 3) * 16 + lr;
                #pragma unroll
                for (int r = 0; r < 4; ++r) {
                    const int n = 16 * tn + lg * 4 + r;
                    dst[base + n * 65] = acc[jj][r];
                }
            }
        }
        __syncthreads();
        // ---- edge logits (threads 0..511) ----
        if (t < 512) {
            const int e = t & 127, hh = t >> 7;
            const int s = ib[ISRC + e], d_ = ib[IDST + e];
            const float* av = gatt + (l * kH + hh) * kD;
            const float* pl = sm + XLo + hh * 4160 + s * 65;
            const float* pr = sm + XRo + hh * 4160 + d_ * 65;
            float a0 = 0.f, a1 = 0.f, a2 = 0.f, a3 = 0.f;
            #pragma unroll 4
            for (int dd = 0; dd < 64; dd += 4) {
                float v0 = pl[dd+0] + pr[dd+0]; v0 = (v0 > 0.f) ? v0 : 0.2f * v0;
                float v1 = pl[dd+1] + pr[dd+1]; v1 = (v1 > 0.f) ? v1 : 0.2f * v1;
                float v2 = pl[dd+2] + pr[dd+2]; v2 = (v2 > 0.f) ? v2 : 0.2f * v2;
                float v3 = pl[dd+3] + pr[dd+3]; v3 = (v3 > 0.f) ? v3 : 0.2f * v3;
                a0 = fmaf(av[dd+0], v0, a0);
                a1 = fmaf(av[dd+1], v1, a1);
                a2 = fmaf(av[dd+2], v2, a2);
                a3 = fmaf(av[dd+3], v3, a3);
            }
            sm[LG + hh * 128 + e] = (a0 + a1) + (a2 + a3);
        }
        __syncthreads();
        // ---- segment max & sum ----
        if (t < 256) {
            const int n = t & 63, hh = t >> 6;
            const int i0 = ib[IOFF + n], i1 = ib[IOFF + n + 1];
            float m = -3.0e38f;
            for (int i = i0; i < i1; ++i) m = fmaxf(m, sm[LG + hh * 128 + ib[IEL + i]]);
            float ssum = 0.f;
            for (int i = i0; i < i1; ++i) ssum += __expf(sm[LG + hh * 128 + ib[IEL + i]] - m);
            sm[MB + hh * 64 + n] = m;
            sm[SB + hh * 64 + n] = __builtin_amdgcn_rcpf(ssum);
        }
        __syncthreads();
        // ---- alpha ----
        if (t < 512) {
            const int e = t & 127, hh = t >> 7;
            const int d_ = ib[IDST + e];
            sm[AL + hh * 128 + e] =
                __expf(sm[LG + hh * 128 + e] - sm[MB + hh * 64 + d_]) * sm[SB + hh * 64 + d_];
        }
        __syncthreads();
        // ---- aggregate + head-mean + bias + in-register LayerNorm -> h[n][k] ----
        #pragma unroll
        for (int r = 0; r < 4; ++r) {
            int p = t + 1024 * r;
            int n = p >> 6, dd = p & 63;      // n wave-uniform, dd = lane
            const int i0 = ib[IOFF + n], i1 = ib[IOFF + n + 1];
            float acc = 0.f;
            for (int i = i0; i < i1; ++i) {
                int e = ib[IEL + i];
                int s = ib[ISRC + e];
                const float* xs = sm + XLo + s * 65 + dd;
                acc = fmaf(sm[AL + 0 * 128 + e], xs[0 * 4160], acc);
                acc = fmaf(sm[AL + 1 * 128 + e], xs[1 * 4160], acc);
                acc = fmaf(sm[AL + 2 * 128 + e], xs[2 * 4160], acc);
                acc = fmaf(sm[AL + 3 * 128 + e], xs[3 * 4160], acc);
            }
            float v = acc * 0.25f + gb[l * kD + dd];
            float s1 = v, s2 = v * v;
            #pragma unroll
            for (int m = 1; m < 64; m <<= 1) {
                s1 += __shfl_xor(s1, m);
                s2 += __shfl_xor(s2, m);
            }
            float mu  = s1 * (1.f / 64.f);
            float var = s2 * (1.f / 64.f) - mu * mu;
            float rs  = rsqrtf(var + 1e-5f);
            float y   = fmaf(lng[l * kD + dd] * (v - mu), rs, lnb[l * kD + dd]);
            sm[HN + n * 68 + dd] = fmaxf(y, 0.f);
        }
        __syncthreads();
    }
    // ---- global mean pool ----
    if (t < kD) {
        float s = 0.f;
        #pragma unroll 8
        for (int n = 0; n < kN; ++n) s += sm[HN + n * 68 + t];
        emb[g * kD + t] = s * (1.f / 64.f);
    }
}

// =====================================================================
// LSTM (2 layers, T=32) + MLP head (UNCHANGED from R6): one block per
// batch element (16), 512 threads, h/c in registers, 1 barrier/step.
// =====================================================================
__global__ __launch_bounds__(512, 1)
void lstm_head_kernel(const float* __restrict__ emb,
                      const float* __restrict__ W0ih, const float* __restrict__ W0hh,
                      const float* __restrict__ b0ih, const float* __restrict__ b0hh,
                      const float* __restrict__ W1ih, const float* __restrict__ W1hh,
                      const float* __restrict__ b1ih, const float* __restrict__ b1hh,
                      const float* __restrict__ hW1, const float* __restrict__ hb1,
                      const float* __restrict__ hW2, const float* __restrict__ hb2,
                      const float* __restrict__ hW3, const float* __restrict__ hb3,
                      float* __restrict__ outp)
{
    extern __shared__ float sm[];
    const int bb = blockIdx.x;
    const int j  = threadIdx.x;      // 0..511
    const int ln = j & 63;
    const int gate = j >> 7;         // 0:i 1:f 2:g 3:o (wave-uniform)

    ((float4*)(sm + ES))[j] = ((const float4*)(emb + bb * kT * kD))[j];
    __syncthreads();

    // ---- layer0 x-part ----
    {
        float w[64];
        const float4* wr = (const float4*)(W0ih + j * 64);
        #pragma unroll
        for (int k4 = 0; k4 < 16; ++k4) {
            float4 v = wr[k4];
            w[4*k4+0] = v.x; w[4*k4+1] = v.y; w[4*k4+2] = v.z; w[4*k4+3] = v.w;
        }
        const float bias = b0ih[j] + b0hh[j];
        for (int tt = 0; tt < kT; ++tt) {
            float ev = sm[ES + tt * 64 + ln];
            float a0 = bias, a1 = 0.f, a2 = 0.f, a3 = 0.f;
            #pragma unroll
            for (int k = 0; k < 64; k += 4) {
                a0 = fmaf(w[k + 0], rlane(ev, k + 0), a0);
                a1 = fmaf(w[k + 1], rlane(ev, k + 1), a1);
                a2 = fmaf(w[k + 2], rlane(ev, k + 2), a2);
                a3 = fmaf(w[k + 3], rlane(ev, k + 3), a3);
            }
            sm[ZX + tt * 512 + j] = (a0 + a1) + (a2 + a3);
        }
    }
    __syncthreads();
    // ---- layer0 recurrence ----
    {
        float w[128];
        const float4* wr = (const float4*)(W0hh + j * 128);
        #pragma unroll
        for (int k4 = 0; k4 < 32; ++k4) {
            float4 v = wr[k4];
            w[4*k4+0] = v.x; w[4*k4+1] = v.y; w[4*k4+2] = v.z; w[4*k4+3] = v.w;
        }
        float hlo = 0.f, hhi = 0.f, clo = 0.f, chi = 0.f;
        for (int tt = 0; tt < kT; ++tt) {
            float a0 = sm[ZX + tt * 512 + j], a1 = 0.f, a2 = 0.f, a3 = 0.f;
            #pragma unroll
            for (int k = 0; k < 64; k += 4) {
                a0 = fmaf(w[k + 0], rlane(hlo, k + 0), a0);
                a1 = fmaf(w[k + 1], rlane(hlo, k + 1), a1);
                a2 = fmaf(w[k + 2], rlane(hlo, k + 2), a2);
                a3 = fmaf(w[k + 3], rlane(hlo, k + 3), a3);
            }
            #pragma unroll
            for (int k = 0; k < 64; k += 4) {
                a0 = fmaf(w[64 + k + 0], rlane(hhi, k + 0), a0);
                a1 = fmaf(w[64 + k + 1], rlane(hhi, k + 1), a1);
                a2 = fmaf(w[64 + k + 2], rlane(hhi, k + 2), a2);
                a3 = fmaf(w[64 + k + 3], rlane(hhi, k + 3), a3);
            }
            float zv = (a0 + a1) + (a2 + a3);
            const int zbase = ZB2 + (tt & 1) * 512;
            sm[zbase + j] = (gate == 2) ? ftanh(zv) : fsig(zv);
            __syncthreads();
            float i0 = sm[zbase + ln],      f0 = sm[zbase + 128 + ln];
            float g0 = sm[zbase + 256 + ln], o0 = sm[zbase + 384 + ln];
            float i1 = sm[zbase + 64 + ln],  f1 = sm[zbase + 192 + ln];
            float g1 = sm[zbase + 320 + ln], o1 = sm[zbase + 448 + ln];
            clo = fmaf(f0, clo, i0 * g0);  hlo = o0 * ftanh(clo);
            chi = fmaf(f1, chi, i1 * g1);  hhi = o1 * ftanh(chi);
            if (j < 64) { sm[YS + tt * 128 + ln] = hlo; sm[YS + tt * 128 + 64 + ln] = hhi; }
        }
    }
    __syncthreads();
    // ---- layer1 x-part ----
    {
        float w[128];
        const float4* wr = (const float4*)(W1ih + j * 128);
        #pragma unroll
        for (int k4 = 0; k4 < 32; ++k4) {
            float4 v = wr[k4];
            w[4*k4+0] = v.x; w[4*k4+1] = v.y; w[4*k4+2] = v.z; w[4*k4+3] = v.w;
        }
        const float bias = b1ih[j] + b1hh[j];
        for (int tt = 0; tt < kT; ++tt) {
            float ylo = sm[YS + tt * 128 + ln];
            float yhi = sm[YS + tt * 128 + 64 + ln];
            float a0 = bias, a1 = 0.f, a2 = 0.f, a3 = 0.f;
            #pragma unroll
            for (int k = 0; k < 64; k += 4) {
                a0 = fmaf(w[k + 0], rlane(ylo, k + 0), a0);
                a1 = fmaf(w[k + 1], rlane(ylo, k + 1), a1);
                a2 = fmaf(w[k + 2], rlane(ylo, k + 2), a2);
                a3 = fmaf(w[k + 3], rlane(ylo, k + 3), a3);
            }
            #pragma unroll
            for (int k = 0; k < 64; k += 4) {
                a0 = fmaf(w[64 + k + 0], rlane(yhi, k + 0), a0);
                a1 = fmaf(w[64 + k + 1], rlane(yhi, k + 1), a1);
                a2 = fmaf(w[64 + k + 2], rlane(yhi, k + 2), a2);
                a3 = fmaf(w[64 + k + 3], rlane(yhi, k + 3), a3);
            }
            sm[ZX + tt * 512 + j] = (a0 + a1) + (a2 + a3);
        }
    }
    __syncthreads();
    // ---- layer1 recurrence ----
    {
        float w[128];
        const float4* wr = (const float4*)(W1hh + j * 128);
        #pragma unroll
        for (int k4 = 0; k4 < 32; ++k4) {
            float4 v = wr[k4];
            w[4*k4+0] = v.x; w[4*k4+1] = v.y; w[4*k4+2] = v.z; w[4*k4+3] = v.w;
        }
        float hlo = 0.f, hhi = 0.f, clo = 0.f, chi = 0.f;
        for (int tt = 0; tt < kT; ++tt) {
            float a0 = sm[ZX + tt * 512 + j], a1 = 0.f, a2 = 0.f, a3 = 0.f;
            #pragma unroll
            for (int k = 0; k < 64; k += 4) {
                a0 = fmaf(w[k + 0], rlane(hlo, k + 0), a0);
                a1 = fmaf(w[k + 1], rlane(hlo, k + 1), a1);
                a2 = fmaf(w[k + 2], rlane(hlo, k + 2), a2);
                a3 = fmaf(w[k + 3], rlane(hlo, k + 3), a3);
            }
            #pragma unroll
            for (int k = 0; k < 64; k += 4) {
                a0 = fmaf(w[64 + k + 0], rlane(hhi, k + 0), a0);
                a1 = fmaf(w[64 + k + 1], rlane(hhi, k + 1), a1);
                a2 = fmaf(w[64 + k + 2], rlane(hhi, k + 2), a2);
                a3 = fmaf(w[64 + k + 3], rlane(hhi, k + 3), a3);
            }
            float zv = (a0 + a1) + (a2 + a3);
            const int zbase = ZB2 + (tt & 1) * 512;
            sm[zbase + j] = (gate == 2) ? ftanh(zv) : fsig(zv);
            __syncthreads();
            float i0 = sm[zbase + ln],      f0 = sm[zbase + 128 + ln];
            float g0 = sm[zbase + 256 + ln], o0 = sm[zbase + 384 + ln];
            float i1 = sm[zbase + 64 + ln],  f1 = sm[zbase + 192 + ln];
            float g1 = sm[zbase + 320 + ln], o1 = sm[zbase + 448 + ln];
            clo = fmaf(f0, clo, i0 * g0);  hlo = o0 * ftanh(clo);
            chi = fmaf(f1, chi, i1 * g1);  hhi = o1 * ftanh(chi);
            if (tt == kT - 1 && j < 64) { sm[ES + ln] = hlo; sm[ES + 64 + ln] = hhi; }
        }
    }
    __syncthreads();
    // ---- MLP head ----
    if (j < 64) {
        float a0 = hb1[j], a1 = 0.f;
        #pragma unroll 8
        for (int k = 0; k < 128; k += 2) {
            a0 = fmaf(hW1[j * 128 + k],     sm[ES + k],     a0);
            a1 = fmaf(hW1[j * 128 + k + 1], sm[ES + k + 1], a1);
        }
        sm[ZB2 + j] = fmaxf(a0 + a1, 0.f);
    }
    __syncthreads();
    if (j < 32) {
        float acc = hb2[j];
        #pragma unroll 8
        for (int k = 0; k < 64; ++k) acc = fmaf(hW2[j * 64 + k], sm[ZB2 + k], acc);
        sm[ZB2 + 64 + j] = fmaxf(acc, 0.f);
    }
    __syncthreads();
    if (j == 0) {
        float acc = hb3[0];
        #pragma unroll
        for (int k = 0; k < 32; ++k) acc = fmaf(hW3[k], sm[ZB2 + 64 + k], acc);
        outp[bb] = fsig(acc);
    }
}

extern "C" void kernel_launch(void* const* d_in, const int* in_sizes, int n_in,
                              void* d_out, int out_size, void* d_ws, size_t ws_size,
                              hipStream_t stream) {
    const float* x     = (const float*)d_in[0];
    const int*   eidx  = (const int*)  d_in[1];
    const float* projW = (const float*)d_in[2];
    const float* projb = (const float*)d_in[3];
    const float* gWl   = (const float*)d_in[4];
    const float* gWr   = (const float*)d_in[5];
    const float* gatt  = (const float*)d_in[6];
    const float* gb    = (const float*)d_in[7];
    const float* lng   = (const float*)d_in[8];
    const float* lnb   = (const float*)d_in[9];
    const float* W0ih  = (const float*)d_in[10];
    const float* W0hh  = (const float*)d_in[11];
    const float* b0ih  = (const float*)d_in[12];
    const float* b0hh  = (const float*)d_in[13];
    const float* W1ih  = (const float*)d_in[14];
    const float* W1hh  = (const float*)d_in[15];
    const float* b1ih  = (const float*)d_in[16];
    const float* b1hh  = (const float*)d_in[17];
    const float* hW1   = (const float*)d_in[18];
    const float* hb1   = (const float*)d_in[19];
    const float* hW2   = (const float*)d_in[20];
    const float* hb2   = (const float*)d_in[21];
    const float* hW3   = (const float*)d_in[22];
    const float* hb3   = (const float*)d_in[23];
    float* outp = (float*)d_out;
    float* emb  = (float*)d_ws;   // [512][64] fp32 scratch

    (void)hipFuncSetAttribute((const void*)gat_kernel,
                              hipFuncAttributeMaxDynamicSharedMemorySize, (int)GAT_LDS);
    (void)hipFuncSetAttribute((const void*)lstm_head_kernel,
                              hipFuncAttributeMaxDynamicSharedMemorySize, (int)LSTM_LDS);

    hipLaunchKernelGGL(gat_kernel, dim3(kG), dim3(1024), GAT_LDS, stream,
                       x, eidx, projW, projb, gWl, gWr, gatt, gb, lng, lnb, emb);
    hipLaunchKernelGGL(lstm_head_kernel, dim3(kB), dim3(512), LSTM_LDS, stream,
                       emb, W0ih, W0hh, b0ih, b0hh, W1ih, W1hh, b1ih, b1hh,
                       hW1, hb1, hW2, hb2, hW3, hb3, outp);
}

// Round 8
// 210.083 us; speedup vs baseline: 1.3089x; 1.1652x over previous
//
#include <hip/hip_runtime.h>
#include <math.h>

namespace {

constexpr int kB = 16, kT = 32, kN = 64, kE = 64, kFIN = 2, kD = 64, kH = 4, kL = 2, kSH = 128;
constexpr int kG = kB * kT;    // 512 graphs
constexpr int kET = kE + kN;   // 128 edges incl. self loops

// ---------------- GAT LDS layout (float indices) ----------------
constexpr int HN   = 0;                    // h[n][k] f32, stride 68 (4352)
constexpr int XLo  = HN + 64 * 68;         // xl[4][64*65]
constexpr int XRo  = XLo + 4 * 4160;       // xr[4][64*65]
constexpr int LG   = XRo + 4 * 4160;       // logitT[4][128]
constexpr int AL   = LG + 4 * 128;         // alphaT[4][128]
constexpr int MB   = AL + 4 * 128;         // mT[4][64]
constexpr int SB   = MB + 4 * 64;          // 1/sum T[4][64]
constexpr int FEND = SB + 4 * 64;          // 39168 floats
constexpr int ISRC = 0, IDST = 128, IOFF = 256, IEL = 321;
constexpr int NINT = IEL + 128;            // 449 ints
constexpr size_t GAT_LDS = size_t(FEND) * 4 + size_t(NINT) * 4;  // 158,468 B

// ---------------- LSTM LDS layout (float/u32 indices) ----------------
constexpr int ES   = 0;                    // emb f32 [32][64]; later final-h[128]
constexpr int EMPK = ES + 2048;            // packed emb u32 [32][32]
constexpr int YSPK = EMPK + 1024;          // packed ys  u32 [32][64]
constexpr int ZB2  = YSPK + 2048;          // gate dbuf f32 [2][512]
constexpr int ZX   = ZB2 + 1024;           // zx f32 [32][512]
constexpr int LSTM_FLOATS = ZX + 32 * 512; // 22528
constexpr size_t LSTM_LDS = size_t(LSTM_FLOATS) * 4;  // 90,112 B

typedef _Float16 half8  __attribute__((ext_vector_type(8)));
typedef _Float16 half2v __attribute__((ext_vector_type(2)));
typedef float    f32x4  __attribute__((ext_vector_type(4)));

__device__ __forceinline__ float fsig(float x) {
    return __builtin_amdgcn_rcpf(1.f + __expf(-x));
}
__device__ __forceinline__ float ftanh(float x) {
    return 1.f - 2.f * __builtin_amdgcn_rcpf(1.f + __expf(2.f * x));
}
__device__ __forceinline__ unsigned pk16(float a, float b) {
    return __builtin_bit_cast(unsigned, __builtin_amdgcn_cvt_pkrtz(a, b));
}
__device__ __forceinline__ unsigned rlu(unsigned v, int l) {
    return (unsigned)__builtin_amdgcn_readlane((int)v, l);
}
__device__ __forceinline__ float fdot2(unsigned a, unsigned b, float c) {
    return __builtin_amdgcn_fdot2(__builtin_bit_cast(half2v, a),
                                  __builtin_bit_cast(half2v, b), c, false);
}

} // namespace

// =====================================================================
// GAT kernel: one block per graph, 1024 threads (16 waves).
// MFMA transforms (R7, unchanged). CSR prefix now a wave-0 shfl scan.
// =====================================================================
__global__ __launch_bounds__(1024, 1)
void gat_kernel(const float* __restrict__ x, const int* __restrict__ eidx,
                const float* __restrict__ projW, const float* __restrict__ projb,
                const float* __restrict__ gWl, const float* __restrict__ gWr,
                const float* __restrict__ gatt, const float* __restrict__ gb,
                const float* __restrict__ lng, const float* __restrict__ lnb,
                float* __restrict__ emb)
{
    extern __shared__ float sm[];
    int* ib = (int*)(sm + FEND);
    const int g = blockIdx.x;
    const int t = threadIdx.x;

    // ---- edges + self loops ----
    if (t < kET) {
        int s, d;
        if (t < kE) { s = eidx[g * 2 * kE + t]; d = eidx[g * 2 * kE + kE + t]; }
        else        { s = t - kE; d = s; }
        ib[ISRC + t] = s;
        ib[IDST + t] = d;
    }
    // ---- input projection + ReLU -> h[n][k] (f32, stride 68) ----
    #pragma unroll
    for (int r = 0; r < 4; ++r) {
        int p = t + 1024 * r;
        int d = p & 63, n = p >> 6;
        float x0 = x[g * kN * kFIN + n * kFIN + 0];
        float x1 = x[g * kN * kFIN + n * kFIN + 1];
        float v = fmaf(x0, projW[d * kFIN + 0], fmaf(x1, projW[d * kFIN + 1], projb[d]));
        sm[HN + n * 68 + d] = fmaxf(v, 0.f);
    }
    __syncthreads();
    // ---- CSR build: count + wave-0 shfl_up inclusive scan ----
    if (t < kN) {
        int c = 0;
        for (int e = 0; e < kET; ++e) c += (ib[IDST + e] == t) ? 1 : 0;
        int s = c;
        #pragma unroll
        for (int d = 1; d < 64; d <<= 1) {
            int v = __shfl_up(s, d);
            if (t >= d) s += v;
        }
        ib[IOFF + t + 1] = s;
        if (t == 0) ib[IOFF + 0] = 0;
    }
    __syncthreads();
    if (t < kN) {
        int pos = ib[IOFF + t];
        for (int e = 0; e < kET; ++e)
            if (ib[IDST + e] == t) ib[IEL + pos++] = e;
    }
    __syncthreads();

    const int wv  = t >> 6;       // wave 0..15
    const int ln  = t & 63;
    const int tn  = wv & 3;       // n-tile (16 rows)
    const int tcg = wv >> 2;      // c-tile group
    const int lr  = ln & 15;
    const int lg  = ln >> 4;

    for (int l = 0; l < kL; ++l) {
        // ======== transforms (MFMA f16): half 0 -> xl, half 1 -> xr ========
        for (int half = 0; half < 2; ++half) {
            const float* Wg = (half ? gWr : gWl) + l * 256 * 64;
            f32x4 acc[4];
            #pragma unroll
            for (int jj = 0; jj < 4; ++jj) acc[jj] = (f32x4){0.f, 0.f, 0.f, 0.f};
            #pragma unroll
            for (int q = 0; q < 2; ++q) {
                const int kb = q * 32 + lg * 8;
                const float* hp = &sm[HN + (16 * tn + lr) * 68 + kb];
                float4 hu = *(const float4*)hp;
                float4 hv = *(const float4*)(hp + 4);
                half8 af;
                af[0] = (_Float16)hu.x; af[1] = (_Float16)hu.y;
                af[2] = (_Float16)hu.z; af[3] = (_Float16)hu.w;
                af[4] = (_Float16)hv.x; af[5] = (_Float16)hv.y;
                af[6] = (_Float16)hv.z; af[7] = (_Float16)hv.w;
                #pragma unroll
                for (int jj = 0; jj < 4; ++jj) {
                    const int c = 16 * (tcg + 4 * jj) + lr;
                    const float* wp = Wg + c * 64 + kb;
                    float4 wu = *(const float4*)wp;
                    float4 wz = *(const float4*)(wp + 4);
                    half8 bf;
                    bf[0] = (_Float16)wu.x; bf[1] = (_Float16)wu.y;
                    bf[2] = (_Float16)wu.z; bf[3] = (_Float16)wu.w;
                    bf[4] = (_Float16)wz.x; bf[5] = (_Float16)wz.y;
                    bf[6] = (_Float16)wz.z; bf[7] = (_Float16)wz.w;
                    acc[jj] = __builtin_amdgcn_mfma_f32_16x16x32_f16(af, bf, acc[jj], 0, 0, 0);
                }
            }
            float* dst = sm + (half ? XRo : XLo);
            #pragma unroll
            for (int jj = 0; jj < 4; ++jj) {
                const int tc = tcg + 4 * jj;
                const int base = (tc >> 2) * 4160 + (tc & 3) * 16 + lr;
                #pragma unroll
                for (int r = 0; r < 4; ++r) {
                    const int n = 16 * tn + lg * 4 + r;
                    dst[base + n * 65] = acc[jj][r];
                }
            }
        }
        __syncthreads();
        // ---- edge logits ----
        if (t < 512) {
            const int e = t & 127, hh = t >> 7;
            const int s = ib[ISRC + e], d_ = ib[IDST + e];
            const float* av = gatt + (l * kH + hh) * kD;
            const float* pl = sm + XLo + hh * 4160 + s * 65;
            const float* pr = sm + XRo + hh * 4160 + d_ * 65;
            float a0 = 0.f, a1 = 0.f, a2 = 0.f, a3 = 0.f;
            #pragma unroll 4
            for (int dd = 0; dd < 64; dd += 4) {
                float v0 = pl[dd+0] + pr[dd+0]; v0 = (v0 > 0.f) ? v0 : 0.2f * v0;
                float v1 = pl[dd+1] + pr[dd+1]; v1 = (v1 > 0.f) ? v1 : 0.2f * v1;
                float v2 = pl[dd+2] + pr[dd+2]; v2 = (v2 > 0.f) ? v2 : 0.2f * v2;
                float v3 = pl[dd+3] + pr[dd+3]; v3 = (v3 > 0.f) ? v3 : 0.2f * v3;
                a0 = fmaf(av[dd+0], v0, a0);
                a1 = fmaf(av[dd+1], v1, a1);
                a2 = fmaf(av[dd+2], v2, a2);
                a3 = fmaf(av[dd+3], v3, a3);
            }
            sm[LG + hh * 128 + e] = (a0 + a1) + (a2 + a3);
        }
        __syncthreads();
        // ---- segment max & sum ----
        if (t < 256) {
            const int n = t & 63, hh = t >> 6;
            const int i0 = ib[IOFF + n], i1 = ib[IOFF + n + 1];
            float m = -3.0e38f;
            for (int i = i0; i < i1; ++i) m = fmaxf(m, sm[LG + hh * 128 + ib[IEL + i]]);
            float ssum = 0.f;
            for (int i = i0; i < i1; ++i) ssum += __expf(sm[LG + hh * 128 + ib[IEL + i]] - m);
            sm[MB + hh * 64 + n] = m;
            sm[SB + hh * 64 + n] = __builtin_amdgcn_rcpf(ssum);
        }
        __syncthreads();
        // ---- alpha ----
        if (t < 512) {
            const int e = t & 127, hh = t >> 7;
            const int d_ = ib[IDST + e];
            sm[AL + hh * 128 + e] =
                __expf(sm[LG + hh * 128 + e] - sm[MB + hh * 64 + d_]) * sm[SB + hh * 64 + d_];
        }
        __syncthreads();
        // ---- aggregate + head-mean + bias + in-register LayerNorm -> h[n][k] ----
        #pragma unroll
        for (int r = 0; r < 4; ++r) {
            int p = t + 1024 * r;
            int n = p >> 6, dd = p & 63;
            const int i0 = ib[IOFF + n], i1 = ib[IOFF + n + 1];
            float acc = 0.f;
            for (int i = i0; i < i1; ++i) {
                int e = ib[IEL + i];
                int s = ib[ISRC + e];
                const float* xs = sm + XLo + s * 65 + dd;
                acc = fmaf(sm[AL + 0 * 128 + e], xs[0 * 4160], acc);
                acc = fmaf(sm[AL + 1 * 128 + e], xs[1 * 4160], acc);
                acc = fmaf(sm[AL + 2 * 128 + e], xs[2 * 4160], acc);
                acc = fmaf(sm[AL + 3 * 128 + e], xs[3 * 4160], acc);
            }
            float v = acc * 0.25f + gb[l * kD + dd];
            float s1 = v, s2 = v * v;
            #pragma unroll
            for (int m = 1; m < 64; m <<= 1) {
                s1 += __shfl_xor(s1, m);
                s2 += __shfl_xor(s2, m);
            }
            float mu  = s1 * (1.f / 64.f);
            float var = s2 * (1.f / 64.f) - mu * mu;
            float rs  = rsqrtf(var + 1e-5f);
            float y   = fmaf(lng[l * kD + dd] * (v - mu), rs, lnb[l * kD + dd]);
            sm[HN + n * 68 + dd] = fmaxf(y, 0.f);
        }
        __syncthreads();
    }
    // ---- global mean pool ----
    if (t < kD) {
        float s = 0.f;
        #pragma unroll 8
        for (int n = 0; n < kN; ++n) s += sm[HN + n * 68 + t];
        emb[g * kD + t] = s * (1.f / 64.f);
    }
}

// =====================================================================
// LSTM (2 layers, T=32) + MLP head: one block per batch (16), 512 thr.
// All dots via v_dot2_f32_f16 (packed f16 pairs): one readlane + one
// dot2 per TWO MACs. Lane ln owns hidden units (2ln, 2ln+1); h packed
// in-register each step (cvt_pkrtz). One barrier per step.
// =====================================================================
__global__ __launch_bounds__(512, 1)
void lstm_head_kernel(const float* __restrict__ emb,
                      const float* __restrict__ W0ih, const float* __restrict__ W0hh,
                      const float* __restrict__ b0ih, const float* __restrict__ b0hh,
                      const float* __restrict__ W1ih, const float* __restrict__ W1hh,
                      const float* __restrict__ b1ih, const float* __restrict__ b1hh,
                      const float* __restrict__ hW1, const float* __restrict__ hb1,
                      const float* __restrict__ hW2, const float* __restrict__ hb2,
                      const float* __restrict__ hW3, const float* __restrict__ hb3,
                      float* __restrict__ outp)
{
    extern __shared__ float sm[];
    unsigned* smu = (unsigned*)sm;
    const int bb = blockIdx.x;
    const int j  = threadIdx.x;      // 0..511
    const int ln = j & 63;
    const int gate = j >> 7;         // 0:i 1:f 2:g 3:o (wave-uniform)

    ((float4*)(sm + ES))[j] = ((const float4*)(emb + bb * kT * kD))[j];
    __syncthreads();
    // pack emb -> EMPK[32t][32 pairs]
    #pragma unroll
    for (int r = 0; r < 2; ++r) {
        int w = j + 512 * r;
        int tt = w >> 5, i = w & 31;
        smu[EMPK + w] = pk16(sm[ES + tt * 64 + 2 * i], sm[ES + tt * 64 + 2 * i + 1]);
    }
    __syncthreads();

    // ---- layer0 x-part: zx[t][j] = bias + W0ih[j,:]·emb[t,:] ----
    {
        unsigned wpk[32];
        const float4* wr = (const float4*)(W0ih + j * 64);
        #pragma unroll
        for (int k4 = 0; k4 < 16; ++k4) {
            float4 v = wr[k4];
            wpk[2 * k4]     = pk16(v.x, v.y);
            wpk[2 * k4 + 1] = pk16(v.z, v.w);
        }
        const float bias = b0ih[j] + b0hh[j];
        for (int tt = 0; tt < kT; ++tt) {
            unsigned ev = smu[EMPK + tt * 32 + (ln & 31)];  // lane q<32 holds pair q
            float a0 = bias, a1 = 0.f, a2 = 0.f, a3 = 0.f;
            #pragma unroll
            for (int q = 0; q < 32; q += 4) {
                a0 = fdot2(wpk[q + 0], rlu(ev, q + 0), a0);
                a1 = fdot2(wpk[q + 1], rlu(ev, q + 1), a1);
                a2 = fdot2(wpk[q + 2], rlu(ev, q + 2), a2);
                a3 = fdot2(wpk[q + 3], rlu(ev, q + 3), a3);
            }
            sm[ZX + tt * 512 + j] = (a0 + a1) + (a2 + a3);
        }
    }
    __syncthreads();
    // ---- layer0 recurrence ----
    {
        unsigned wpk[64];
        const float4* wr = (const float4*)(W0hh + j * 128);
        #pragma unroll
        for (int k4 = 0; k4 < 32; ++k4) {
            float4 v = wr[k4];
            wpk[2 * k4]     = pk16(v.x, v.y);
            wpk[2 * k4 + 1] = pk16(v.z, v.w);
        }
        unsigned hpk = 0;
        float c0 = 0.f, c1 = 0.f;
        for (int tt = 0; tt < kT; ++tt) {
            float a0 = sm[ZX + tt * 512 + j], a1 = 0.f, a2 = 0.f, a3 = 0.f;
            #pragma unroll
            for (int q = 0; q < 64; q += 4) {
                a0 = fdot2(wpk[q + 0], rlu(hpk, q + 0), a0);
                a1 = fdot2(wpk[q + 1], rlu(hpk, q + 1), a1);
                a2 = fdot2(wpk[q + 2], rlu(hpk, q + 2), a2);
                a3 = fdot2(wpk[q + 3], rlu(hpk, q + 3), a3);
            }
            float zv = (a0 + a1) + (a2 + a3);
            const int zbase = ZB2 + (tt & 1) * 512;
            sm[zbase + j] = (gate == 2) ? ftanh(zv) : fsig(zv);
            __syncthreads();
            float2 ig = *(const float2*)&sm[zbase + 2 * ln];
            float2 fg = *(const float2*)&sm[zbase + 128 + 2 * ln];
            float2 gg = *(const float2*)&sm[zbase + 256 + 2 * ln];
            float2 og = *(const float2*)&sm[zbase + 384 + 2 * ln];
            c0 = fmaf(fg.x, c0, ig.x * gg.x);
            c1 = fmaf(fg.y, c1, ig.y * gg.y);
            float h0 = og.x * ftanh(c0);
            float h1 = og.y * ftanh(c1);
            hpk = pk16(h0, h1);
            if (j < 64) smu[YSPK + tt * 64 + ln] = hpk;
        }
    }
    __syncthreads();
    // ---- layer1 x-part: zx[t][j] = bias + W1ih[j,:]·ys[t,:] ----
    {
        unsigned wpk[64];
        const float4* wr = (const float4*)(W1ih + j * 128);
        #pragma unroll
        for (int k4 = 0; k4 < 32; ++k4) {
            float4 v = wr[k4];
            wpk[2 * k4]     = pk16(v.x, v.y);
            wpk[2 * k4 + 1] = pk16(v.z, v.w);
        }
        const float bias = b1ih[j] + b1hh[j];
        for (int tt = 0; tt < kT; ++tt) {
            unsigned yv = smu[YSPK + tt * 64 + ln];         // lane q holds pair q
            float a0 = bias, a1 = 0.f, a2 = 0.f, a3 = 0.f;
            #pragma unroll
            for (int q = 0; q < 64; q += 4) {
                a0 = fdot2(wpk[q + 0], rlu(yv, q + 0), a0);
                a1 = fdot2(wpk[q + 1], rlu(yv, q + 1), a1);
                a2 = fdot2(wpk[q + 2], rlu(yv, q + 2), a2);
                a3 = fdot2(wpk[q + 3], rlu(yv, q + 3), a3);
            }
            sm[ZX + tt * 512 + j] = (a0 + a1) + (a2 + a3);
        }
    }
    __syncthreads();
    // ---- layer1 recurrence (final h only) ----
    {
        unsigned wpk[64];
        const float4* wr = (const float4*)(W1hh + j * 128);
        #pragma unroll
        for (int k4 = 0; k4 < 32; ++k4) {
            float4 v = wr[k4];
            wpk[2 * k4]     = pk16(v.x, v.y);
            wpk[2 * k4 + 1] = pk16(v.z, v.w);
        }
        unsigned hpk = 0;
        float c0 = 0.f, c1 = 0.f;
        for (int tt = 0; tt < kT; ++tt) {
            float a0 = sm[ZX + tt * 512 + j], a1 = 0.f, a2 = 0.f, a3 = 0.f;
            #pragma unroll
            for (int q = 0; q < 64; q += 4) {
                a0 = fdot2(wpk[q + 0], rlu(hpk, q + 0), a0);
                a1 = fdot2(wpk[q + 1], rlu(hpk, q + 1), a1);
                a2 = fdot2(wpk[q + 2], rlu(hpk, q + 2), a2);
                a3 = fdot2(wpk[q + 3], rlu(hpk, q + 3), a3);
            }
            float zv = (a0 + a1) + (a2 + a3);
            const int zbase = ZB2 + (tt & 1) * 512;
            sm[zbase + j] = (gate == 2) ? ftanh(zv) : fsig(zv);
            __syncthreads();
            float2 ig = *(const float2*)&sm[zbase + 2 * ln];
            float2 fg = *(const float2*)&sm[zbase + 128 + 2 * ln];
            float2 gg = *(const float2*)&sm[zbase + 256 + 2 * ln];
            float2 og = *(const float2*)&sm[zbase + 384 + 2 * ln];
            c0 = fmaf(fg.x, c0, ig.x * gg.x);
            c1 = fmaf(fg.y, c1, ig.y * gg.y);
            float h0 = og.x * ftanh(c0);
            float h1 = og.y * ftanh(c1);
            hpk = pk16(h0, h1);
            if (tt == kT - 1 && j < 64) { sm[ES + 2 * ln] = h0; sm[ES + 2 * ln + 1] = h1; }
        }
    }
    __syncthreads();
    // ---- MLP head (final h f32 in sm[ES..ES+128)) ----
    if (j < 64) {
        float a0 = hb1[j], a1 = 0.f;
        #pragma unroll 8
        for (int k = 0; k < 128; k += 2) {
            a0 = fmaf(hW1[j * 128 + k],     sm[ES + k],     a0);
            a1 = fmaf(hW1[j * 128 + k + 1], sm[ES + k + 1], a1);
        }
        sm[ZB2 + j] = fmaxf(a0 + a1, 0.f);
    }
    __syncthreads();
    if (j < 32) {
        float acc = hb2[j];
        #pragma unroll 8
        for (int k = 0; k < 64; ++k) acc = fmaf(hW2[j * 64 + k], sm[ZB2 + k], acc);
        sm[ZB2 + 64 + j] = fmaxf(acc, 0.f);
    }
    __syncthreads();
    if (j == 0) {
        float acc = hb3[0];
        #pragma unroll
        for (int k = 0; k < 32; ++k) acc = fmaf(hW3[k], sm[ZB2 + 64 + k], acc);
        outp[bb] = fsig(acc);
    }
}

extern "C" void kernel_launch(void* const* d_in, const int* in_sizes, int n_in,
                              void* d_out, int out_size, void* d_ws, size_t ws_size,
                              hipStream_t stream) {
    const float* x     = (const float*)d_in[0];
    const int*   eidx  = (const int*)  d_in[1];
    const float* projW = (const float*)d_in[2];
    const float* projb = (const float*)d_in[3];
    const float* gWl   = (const float*)d_in[4];
    const float* gWr   = (const float*)d_in[5];
    const float* gatt  = (const float*)d_in[6];
    const float* gb    = (const float*)d_in[7];
    const float* lng   = (const float*)d_in[8];
    const float* lnb   = (const float*)d_in[9];
    const float* W0ih  = (const float*)d_in[10];
    const float* W0hh  = (const float*)d_in[11];
    const float* b0ih  = (const float*)d_in[12];
    const float* b0hh  = (const float*)d_in[13];
    const float* W1ih  = (const float*)d_in[14];
    const float* W1hh  = (const float*)d_in[15];
    const float* b1ih  = (const float*)d_in[16];
    const float* b1hh  = (const float*)d_in[17];
    const float* hW1   = (const float*)d_in[18];
    const float* hb1   = (const float*)d_in[19];
    const float* hW2   = (const float*)d_in[20];
    const float* hb2   = (const float*)d_in[21];
    const float* hW3   = (const float*)d_in[22];
    const float* hb3   = (const float*)d_in[23];
    float* outp = (float*)d_out;
    float* emb  = (float*)d_ws;   // [512][64] fp32 scratch

    (void)hipFuncSetAttribute((const void*)gat_kernel,
                              hipFuncAttributeMaxDynamicSharedMemorySize, (int)GAT_LDS);
    (void)hipFuncSetAttribute((const void*)lstm_head_kernel,
                              hipFuncAttributeMaxDynamicSharedMemorySize, (int)LSTM_LDS);

    hipLaunchKernelGGL(gat_kernel, dim3(kG), dim3(1024), GAT_LDS, stream,
                       x, eidx, projW, projb, gWl, gWr, gatt, gb, lng, lnb, emb);
    hipLaunchKernelGGL(lstm_head_kernel, dim3(kB), dim3(512), LSTM_LDS, stream,
                       emb, W0ih, W0hh, b0ih, b0hh, W1ih, W1hh, b1ih, b1hh,
                       hW1, hb1, hW2, hb2, hW3, hb3, outp);
}

// Round 11
// 209.754 us; speedup vs baseline: 1.3109x; 1.0016x over previous
//
#include <hip/hip_runtime.h>
#include <math.h>

namespace {

constexpr int kB = 16, kT = 32, kN = 64, kE = 64, kFIN = 2, kD = 64, kH = 4, kL = 2, kSH = 128;
constexpr int kG = kB * kT;    // 512 graphs
constexpr int kET = kE + kN;   // 128 edges incl. self loops

// ---------------- GAT LDS layout (BYTE offsets) ----------------
// f16 tensors use a 16B-slot XOR swizzle: element (row, dd) lives at
// half-index row*64 + ((dd>>3)^(row&7))*8 + (dd&7).
constexpr int HNH_B = 0;          // h    f16 [64][64] swizzled (8192 B)
constexpr int XLH_B = 8192;       // xl   f16 [2][64][64] swizzled (16384 B)
constexpr int XRH_B = 24576;      // xr   f16 [2][64][64] swizzled (16384 B)
constexpr int TMP_B = 40960;      // tmp  f32 [64][66] (16896 B)
constexpr int LG_B  = 57856;      // logit f32 [2][128] (1024 B)
constexpr int AL_B  = 58880;      // alpha f32 [2][128] (1024 B)
constexpr int MB_B  = 59904;      // max   f32 [2][64] (512 B)
constexpr int SB_B  = 60416;      // 1/sum f32 [2][64] (512 B)
constexpr int IB_B  = 60928;      // ints [449] (1796 B)
constexpr size_t GAT_LDS = IB_B + 449 * 4;   // 62,724 B -> 2 blocks/CU
constexpr int ISRC = 0, IDST = 128, IOFF = 256, IEL = 321;

// ---------------- LSTM LDS layout (float/u32 indices) ----------------
constexpr int ES   = 0;                    // emb f32 [32][64]; later final-h[128]
constexpr int EMPK = ES + 2048;            // packed emb u32 [32][32]
constexpr int YSPK = EMPK + 1024;          // packed ys  u32 [32][64]
constexpr int ZB2  = YSPK + 2048;          // gate dbuf f32 [2][512]
constexpr int ZX   = ZB2 + 1024;           // zx f32 [32][512]
constexpr int LSTM_FLOATS = ZX + 32 * 512;
constexpr size_t LSTM_LDS = size_t(LSTM_FLOATS) * 4;  // 90,112 B

typedef _Float16 half8  __attribute__((ext_vector_type(8)));
typedef _Float16 half2v __attribute__((ext_vector_type(2)));
typedef float    f32x4  __attribute__((ext_vector_type(4)));

__device__ __forceinline__ float fsig(float x) {
    return __builtin_amdgcn_rcpf(1.f + __expf(-x));
}
__device__ __forceinline__ float ftanh(float x) {
    return 1.f - 2.f * __builtin_amdgcn_rcpf(1.f + __expf(2.f * x));
}
__device__ __forceinline__ unsigned pk16(float a, float b) {
    return __builtin_bit_cast(unsigned, __builtin_amdgcn_cvt_pkrtz(a, b));
}
__device__ __forceinline__ unsigned rlu(unsigned v, int l) {
    return (unsigned)__builtin_amdgcn_readlane((int)v, l);
}
__device__ __forceinline__ float fdot2(unsigned a, unsigned b, float c) {
    return __builtin_amdgcn_fdot2(__builtin_bit_cast(half2v, a),
                                  __builtin_bit_cast(half2v, b), c, false);
}
// swizzled half-index for f16 [64][64] tiles
__device__ __forceinline__ int swz(int row, int dd) {
    return row * 64 + (((dd >> 3) ^ (row & 7)) << 3) + (dd & 7);
}

} // namespace

// =====================================================================
// GAT kernel: one block per graph, 1024 threads, 62.7 KB LDS
// -> 2 blocks/CU co-resident (uncorrelated phases fill each other's
// stalls). Heads processed in 2 pairs; h/xl/xr f16 swizzled; TMP f32
// accumulates across pairs; LN in registers.
// =====================================================================
__global__ __launch_bounds__(1024, 8)   // 8 waves/EU -> VGPR <= 64
void gat_kernel(const float* __restrict__ x, const int* __restrict__ eidx,
                const float* __restrict__ projW, const float* __restrict__ projb,
                const float* __restrict__ gWl, const float* __restrict__ gWr,
                const float* __restrict__ gatt, const float* __restrict__ gb,
                const float* __restrict__ lng, const float* __restrict__ lnb,
                float* __restrict__ emb)
{
    extern __shared__ char smc[];
    _Float16* hn  = (_Float16*)(smc + HNH_B);
    _Float16* xlh = (_Float16*)(smc + XLH_B);
    _Float16* xrh = (_Float16*)(smc + XRH_B);
    float* tmp = (float*)(smc + TMP_B);
    float* lg  = (float*)(smc + LG_B);
    float* al  = (float*)(smc + AL_B);
    float* mb  = (float*)(smc + MB_B);
    float* sb  = (float*)(smc + SB_B);
    int*   ib  = (int*)(smc + IB_B);
    const int g = blockIdx.x;
    const int t = threadIdx.x;

    // ---- edges + self loops ----
    if (t < kET) {
        int s, d;
        if (t < kE) { s = eidx[g * 2 * kE + t]; d = eidx[g * 2 * kE + kE + t]; }
        else        { s = t - kE; d = s; }
        ib[ISRC + t] = s;
        ib[IDST + t] = d;
    }
    // ---- input projection + ReLU -> h (f16, swizzled) ----
    #pragma unroll
    for (int r = 0; r < 4; ++r) {
        int p = t + 1024 * r;
        int d = p & 63, n = p >> 6;
        float x0 = x[g * kN * kFIN + n * kFIN + 0];
        float x1 = x[g * kN * kFIN + n * kFIN + 1];
        float v = fmaf(x0, projW[d * kFIN + 0], fmaf(x1, projW[d * kFIN + 1], projb[d]));
        hn[swz(n, d)] = (_Float16)fmaxf(v, 0.f);
    }
    __syncthreads();
    // ---- CSR build: count + wave-0 shfl_up inclusive scan ----
    if (t < kN) {
        int c = 0;
        for (int e = 0; e < kET; ++e) c += (ib[IDST + e] == t) ? 1 : 0;
        int s = c;
        #pragma unroll
        for (int d = 1; d < 64; d <<= 1) {
            int v = __shfl_up(s, d);
            if (t >= d) s += v;
        }
        ib[IOFF + t + 1] = s;
        if (t == 0) ib[IOFF + 0] = 0;
    }
    __syncthreads();
    if (t < kN) {
        int pos = ib[IOFF + t];
        for (int e = 0; e < kET; ++e)
            if (ib[IDST + e] == t) ib[IEL + pos++] = e;
    }
    __syncthreads();

    const int wv  = t >> 6;       // wave 0..15
    const int ln  = t & 63;
    const int tn  = wv & 3;       // n-tile (16 rows)
    const int tcg = wv >> 2;      // c-tile group (0..3): tiles tcg, tcg+4
    const int lr  = ln & 15;      // A-row / B-col within tile
    const int kg  = ln >> 4;      // k-chunk group 0..3

    for (int l = 0; l < kL; ++l) {
        for (int pr = 0; pr < 2; ++pr) {          // head pair: heads 2pr, 2pr+1
            // ---- transforms (MFMA f16): xl and xr for this pair ----
            {
                f32x4 acc[2][2];
                #pragma unroll
                for (int hf = 0; hf < 2; ++hf)
                    #pragma unroll
                    for (int jj = 0; jj < 2; ++jj) acc[hf][jj] = (f32x4){0.f,0.f,0.f,0.f};
                #pragma unroll
                for (int q = 0; q < 2; ++q) {
                    const int kc = q * 4 + kg;    // logical 8-elem k-chunk
                    const int kb = kc * 8;
                    half8 af = *(const half8*)&hn[(16 * tn + lr) * 64 + ((kc ^ (lr & 7)) << 3)];
                    #pragma unroll
                    for (int hf = 0; hf < 2; ++hf) {
                        const float* Wg = (hf ? gWr : gWl) + l * 256 * 64 + pr * 128 * 64;
                        #pragma unroll
                        for (int jj = 0; jj < 2; ++jj) {
                            const int c = 16 * (tcg + 4 * jj) + lr;
                            const float* wp = Wg + c * 64 + kb;
                            float4 wu = *(const float4*)wp;
                            float4 wz = *(const float4*)(wp + 4);
                            half8 bf;
                            bf[0] = (_Float16)wu.x; bf[1] = (_Float16)wu.y;
                            bf[2] = (_Float16)wu.z; bf[3] = (_Float16)wu.w;
                            bf[4] = (_Float16)wz.x; bf[5] = (_Float16)wz.y;
                            bf[6] = (_Float16)wz.z; bf[7] = (_Float16)wz.w;
                            acc[hf][jj] = __builtin_amdgcn_mfma_f32_16x16x32_f16(af, bf, acc[hf][jj], 0, 0, 0);
                        }
                    }
                }
                #pragma unroll
                for (int hf = 0; hf < 2; ++hf) {
                    _Float16* dst = hf ? xrh : xlh;
                    #pragma unroll
                    for (int jj = 0; jj < 2; ++jj) {
                        const int c  = 16 * (tcg + 4 * jj) + lr;
                        const int dd = c & 63, hl = c >> 6;
                        #pragma unroll
                        for (int r = 0; r < 4; ++r) {
                            const int n = 16 * tn + kg * 4 + r;
                            dst[hl * 4096 + swz(n, dd)] = (_Float16)acc[hf][jj][r];
                        }
                    }
                }
            }
            __syncthreads();
            // ---- edge logits: 256 threads, one (e, head) each ----
            if (t < 256) {
                const int e = t & 127, hh = t >> 7;
                const int s = ib[ISRC + e], d_ = ib[IDST + e];
                const float* av = gatt + (l * kH + 2 * pr + hh) * kD;
                float a0 = 0.f, a1 = 0.f, a2 = 0.f, a3 = 0.f;
                #pragma unroll
                for (int c8 = 0; c8 < 8; ++c8) {
                    half8 xv = *(const half8*)&xlh[hh * 4096 + s  * 64 + ((c8 ^ (s  & 7)) << 3)];
                    half8 rv = *(const half8*)&xrh[hh * 4096 + d_ * 64 + ((c8 ^ (d_ & 7)) << 3)];
                    float4 au = *(const float4*)(av + c8 * 8);
                    float4 az = *(const float4*)(av + c8 * 8 + 4);
                    const float avv[8] = {au.x, au.y, au.z, au.w, az.x, az.y, az.z, az.w};
                    #pragma unroll
                    for (int i = 0; i < 8; ++i) {
                        float v = (float)xv[i] + (float)rv[i];
                        v = (v > 0.f) ? v : 0.2f * v;
                        float* a = (i & 2) ? ((i & 1) ? &a3 : &a2) : ((i & 1) ? &a1 : &a0);
                        *a = fmaf(avv[i], v, *a);
                    }
                }
                lg[hh * 128 + e] = (a0 + a1) + (a2 + a3);
            }
            __syncthreads();
            // ---- segment max & sum: 128 threads ----
            if (t < 128) {
                const int n = t & 63, hh = t >> 6;
                const int i0 = ib[IOFF + n], i1 = ib[IOFF + n + 1];
                float m = -3.0e38f;
                for (int i = i0; i < i1; ++i) m = fmaxf(m, lg[hh * 128 + ib[IEL + i]]);
                float ssum = 0.f;
                for (int i = i0; i < i1; ++i) ssum += __expf(lg[hh * 128 + ib[IEL + i]] - m);
                mb[hh * 64 + n] = m;
                sb[hh * 64 + n] = __builtin_amdgcn_rcpf(ssum);
            }
            __syncthreads();
            // ---- alpha: 256 threads ----
            if (t < 256) {
                const int e = t & 127, hh = t >> 7;
                const int d_ = ib[IDST + e];
                al[hh * 128 + e] = __expf(lg[hh * 128 + e] - mb[hh * 64 + d_]) * sb[hh * 64 + d_];
            }
            __syncthreads();
            // ---- aggregate pair; pair 1 finishes with bias + LN + ReLU ----
            #pragma unroll
            for (int r = 0; r < 4; ++r) {
                int p = t + 1024 * r;
                int n = p >> 6, dd = p & 63;      // n wave-uniform, dd = lane
                const int i0 = ib[IOFF + n], i1 = ib[IOFF + n + 1];
                float acc = 0.f;
                for (int i = i0; i < i1; ++i) {
                    int e = ib[IEL + i];
                    int s = ib[ISRC + e];
                    int si = swz(s, dd);
                    acc = fmaf(al[e],       (float)xlh[si],        acc);
                    acc = fmaf(al[128 + e], (float)xlh[4096 + si], acc);
                }
                if (pr == 0) {
                    tmp[n * 66 + dd] = acc;
                } else {
                    float v = (tmp[n * 66 + dd] + acc) * 0.25f + gb[l * kD + dd];
                    float s1 = v, s2 = v * v;
                    #pragma unroll
                    for (int m = 1; m < 64; m <<= 1) {
                        s1 += __shfl_xor(s1, m);
                        s2 += __shfl_xor(s2, m);
                    }
                    float mu  = s1 * (1.f / 64.f);
                    float var = s2 * (1.f / 64.f) - mu * mu;
                    float rs  = rsqrtf(var + 1e-5f);
                    float y   = fmaf(lng[l * kD + dd] * (v - mu), rs, lnb[l * kD + dd]);
                    hn[swz(n, dd)] = (_Float16)fmaxf(y, 0.f);
                }
            }
            __syncthreads();
        } // pair
    } // layer
    // ---- global mean pool ----
    if (t < kD) {
        float s = 0.f;
        #pragma unroll 8
        for (int n = 0; n < kN; ++n) s += (float)hn[swz(n, t)];
        emb[g * kD + t] = s * (1.f / 64.f);
    }
}

// =====================================================================
// LSTM (2 layers, T=32) + MLP head (UNCHANGED from R8): one block per
// batch (16), 512 threads, fdot2 packed-f16 dots, 1 barrier/step.
// =====================================================================
__global__ __launch_bounds__(512, 1)
void lstm_head_kernel(const float* __restrict__ emb,
                      const float* __restrict__ W0ih, const float* __restrict__ W0hh,
                      const float* __restrict__ b0ih, const float* __restrict__ b0hh,
                      const float* __restrict__ W1ih, const float* __restrict__ W1hh,
                      const float* __restrict__ b1ih, const float* __restrict__ b1hh,
                      const float* __restrict__ hW1, const float* __restrict__ hb1,
                      const float* __restrict__ hW2, const float* __restrict__ hb2,
                      const float* __restrict__ hW3, const float* __restrict__ hb3,
                      float* __restrict__ outp)
{
    extern __shared__ float sm[];
    unsigned* smu = (unsigned*)sm;
    const int bb = blockIdx.x;
    const int j  = threadIdx.x;      // 0..511
    const int ln = j & 63;
    const int gate = j >> 7;         // 0:i 1:f 2:g 3:o (wave-uniform)

    ((float4*)(sm + ES))[j] = ((const float4*)(emb + bb * kT * kD))[j];
    __syncthreads();
    #pragma unroll
    for (int r = 0; r < 2; ++r) {
        int w = j + 512 * r;
        int tt = w >> 5, i = w & 31;
        smu[EMPK + w] = pk16(sm[ES + tt * 64 + 2 * i], sm[ES + tt * 64 + 2 * i + 1]);
    }
    __syncthreads();

    // ---- layer0 x-part ----
    {
        unsigned wpk[32];
        const float4* wr = (const float4*)(W0ih + j * 64);
        #pragma unroll
        for (int k4 = 0; k4 < 16; ++k4) {
            float4 v = wr[k4];
            wpk[2 * k4]     = pk16(v.x, v.y);
            wpk[2 * k4 + 1] = pk16(v.z, v.w);
        }
        const float bias = b0ih[j] + b0hh[j];
        for (int tt = 0; tt < kT; ++tt) {
            unsigned ev = smu[EMPK + tt * 32 + (ln & 31)];
            float a0 = bias, a1 = 0.f, a2 = 0.f, a3 = 0.f;
            #pragma unroll
            for (int q = 0; q < 32; q += 4) {
                a0 = fdot2(wpk[q + 0], rlu(ev, q + 0), a0);
                a1 = fdot2(wpk[q + 1], rlu(ev, q + 1), a1);
                a2 = fdot2(wpk[q + 2], rlu(ev, q + 2), a2);
                a3 = fdot2(wpk[q + 3], rlu(ev, q + 3), a3);
            }
            sm[ZX + tt * 512 + j] = (a0 + a1) + (a2 + a3);
        }
    }
    __syncthreads();
    // ---- layer0 recurrence ----
    {
        unsigned wpk[64];
        const float4* wr = (const float4*)(W0hh + j * 128);
        #pragma unroll
        for (int k4 = 0; k4 < 32; ++k4) {
            float4 v = wr[k4];
            wpk[2 * k4]     = pk16(v.x, v.y);
            wpk[2 * k4 + 1] = pk16(v.z, v.w);
        }
        unsigned hpk = 0;
        float c0 = 0.f, c1 = 0.f;
        for (int tt = 0; tt < kT; ++tt) {
            float a0 = sm[ZX + tt * 512 + j], a1 = 0.f, a2 = 0.f, a3 = 0.f;
            #pragma unroll
            for (int q = 0; q < 64; q += 4) {
                a0 = fdot2(wpk[q + 0], rlu(hpk, q + 0), a0);
                a1 = fdot2(wpk[q + 1], rlu(hpk, q + 1), a1);
                a2 = fdot2(wpk[q + 2], rlu(hpk, q + 2), a2);
                a3 = fdot2(wpk[q + 3], rlu(hpk, q + 3), a3);
            }
            float zv = (a0 + a1) + (a2 + a3);
            const int zbase = ZB2 + (tt & 1) * 512;
            sm[zbase + j] = (gate == 2) ? ftanh(zv) : fsig(zv);
            __syncthreads();
            float2 ig = *(const float2*)&sm[zbase + 2 * ln];
            float2 fg = *(const float2*)&sm[zbase + 128 + 2 * ln];
            float2 gg = *(const float2*)&sm[zbase + 256 + 2 * ln];
            float2 og = *(const float2*)&sm[zbase + 384 + 2 * ln];
            c0 = fmaf(fg.x, c0, ig.x * gg.x);
            c1 = fmaf(fg.y, c1, ig.y * gg.y);
            float h0 = og.x * ftanh(c0);
            float h1 = og.y * ftanh(c1);
            hpk = pk16(h0, h1);
            if (j < 64) smu[YSPK + tt * 64 + ln] = hpk;
        }
    }
    __syncthreads();
    // ---- layer1 x-part ----
    {
        unsigned wpk[64];
        const float4* wr = (const float4*)(W1ih + j * 128);
        #pragma unroll
        for (int k4 = 0; k4 < 32; ++k4) {
            float4 v = wr[k4];
            wpk[2 * k4]     = pk16(v.x, v.y);
            wpk[2 * k4 + 1] = pk16(v.z, v.w);
        }
        const float bias = b1ih[j] + b1hh[j];
        for (int tt = 0; tt < kT; ++tt) {
            unsigned yv = smu[YSPK + tt * 64 + ln];
            float a0 = bias, a1 = 0.f, a2 = 0.f, a3 = 0.f;
            #pragma unroll
            for (int q = 0; q < 64; q += 4) {
                a0 = fdot2(wpk[q + 0], rlu(yv, q + 0), a0);
                a1 = fdot2(wpk[q + 1], rlu(yv, q + 1), a1);
                a2 = fdot2(wpk[q + 2], rlu(yv, q + 2), a2);
                a3 = fdot2(wpk[q + 3], rlu(yv, q + 3), a3);
            }
            sm[ZX + tt * 512 + j] = (a0 + a1) + (a2 + a3);
        }
    }
    __syncthreads();
    // ---- layer1 recurrence (final h only) ----
    {
        unsigned wpk[64];
        const float4* wr = (const float4*)(W1hh + j * 128);
        #pragma unroll
        for (int k4 = 0; k4 < 32; ++k4) {
            float4 v = wr[k4];
            wpk[2 * k4]     = pk16(v.x, v.y);
            wpk[2 * k4 + 1] = pk16(v.z, v.w);
        }
        unsigned hpk = 0;
        float c0 = 0.f, c1 = 0.f;
        for (int tt = 0; tt < kT; ++tt) {
            float a0 = sm[ZX + tt * 512 + j], a1 = 0.f, a2 = 0.f, a3 = 0.f;
            #pragma unroll
            for (int q = 0; q < 64; q += 4) {
                a0 = fdot2(wpk[q + 0], rlu(hpk, q + 0), a0);
                a1 = fdot2(wpk[q + 1], rlu(hpk, q + 1), a1);
                a2 = fdot2(wpk[q + 2], rlu(hpk, q + 2), a2);
                a3 = fdot2(wpk[q + 3], rlu(hpk, q + 3), a3);
            }
            float zv = (a0 + a1) + (a2 + a3);
            const int zbase = ZB2 + (tt & 1) * 512;
            sm[zbase + j] = (gate == 2) ? ftanh(zv) : fsig(zv);
            __syncthreads();
            float2 ig = *(const float2*)&sm[zbase + 2 * ln];
            float2 fg = *(const float2*)&sm[zbase + 128 + 2 * ln];
            float2 gg = *(const float2*)&sm[zbase + 256 + 2 * ln];
            float2 og = *(const float2*)&sm[zbase + 384 + 2 * ln];
            c0 = fmaf(fg.x, c0, ig.x * gg.x);
            c1 = fmaf(fg.y, c1, ig.y * gg.y);
            float h0 = og.x * ftanh(c0);
            float h1 = og.y * ftanh(c1);
            hpk = pk16(h0, h1);
            if (tt == kT - 1 && j < 64) { sm[ES + 2 * ln] = h0; sm[ES + 2 * ln + 1] = h1; }
        }
    }
    __syncthreads();
    // ---- MLP head ----
    if (j < 64) {
        float a0 = hb1[j], a1 = 0.f;
        #pragma unroll 8
        for (int k = 0; k < 128; k += 2) {
            a0 = fmaf(hW1[j * 128 + k],     sm[ES + k],     a0);
            a1 = fmaf(hW1[j * 128 + k + 1], sm[ES + k + 1], a1);
        }
        sm[ZB2 + j] = fmaxf(a0 + a1, 0.f);
    }
    __syncthreads();
    if (j < 32) {
        float acc = hb2[j];
        #pragma unroll 8
        for (int k = 0; k < 64; ++k) acc = fmaf(hW2[j * 64 + k], sm[ZB2 + k], acc);
        sm[ZB2 + 64 + j] = fmaxf(acc, 0.f);
    }
    __syncthreads();
    if (j == 0) {
        float acc = hb3[0];
        #pragma unroll
        for (int k = 0; k < 32; ++k) acc = fmaf(hW3[k], sm[ZB2 + 64 + k], acc);
        outp[bb] = fsig(acc);
    }
}

extern "C" void kernel_launch(void* const* d_in, const int* in_sizes, int n_in,
                              void* d_out, int out_size, void* d_ws, size_t ws_size,
                              hipStream_t stream) {
    const float* x     = (const float*)d_in[0];
    const int*   eidx  = (const int*)  d_in[1];
    const float* projW = (const float*)d_in[2];
    const float* projb = (const float*)d_in[3];
    const float* gWl   = (const float*)d_in[4];
    const float* gWr   = (const float*)d_in[5];
    const float* gatt  = (const float*)d_in[6];
    const float* gb    = (const float*)d_in[7];
    const float* lng   = (const float*)d_in[8];
    const float* lnb   = (const float*)d_in[9];
    const float* W0ih  = (const float*)d_in[10];
    const float* W0hh  = (const float*)d_in[11];
    const float* b0ih  = (const float*)d_in[12];
    const float* b0hh  = (const float*)d_in[13];
    const float* W1ih  = (const float*)d_in[14];
    const float* W1hh  = (const float*)d_in[15];
    const float* b1ih  = (const float*)d_in[16];
    const float* b1hh  = (const float*)d_in[17];
    const float* hW1   = (const float*)d_in[18];
    const float* hb1   = (const float*)d_in[19];
    const float* hW2   = (const float*)d_in[20];
    const float* hb2   = (const float*)d_in[21];
    const float* hW3   = (const float*)d_in[22];
    const float* hb3   = (const float*)d_in[23];
    float* outp = (float*)d_out;
    float* emb  = (float*)d_ws;   // [512][64] fp32 scratch

    (void)hipFuncSetAttribute((const void*)gat_kernel,
                              hipFuncAttributeMaxDynamicSharedMemorySize, (int)GAT_LDS);
    (void)hipFuncSetAttribute((const void*)lstm_head_kernel,
                              hipFuncAttributeMaxDynamicSharedMemorySize, (int)LSTM_LDS);

    hipLaunchKernelGGL(gat_kernel, dim3(kG), dim3(1024), GAT_LDS, stream,
                       x, eidx, projW, projb, gWl, gWr, gatt, gb, lng, lnb, emb);
    hipLaunchKernelGGL(lstm_head_kernel, dim3(kB), dim3(512), LSTM_LDS, stream,
                       emb, W0ih, W0hh, b0ih, b0hh, W1ih, W1hh, b1ih, b1hh,
                       hW1, hb1, hW2, hb2, hW3, hb3, outp);
}